// Round 6
// baseline (420.828 us; speedup 1.0000x reference)
//
#include <hip/hip_runtime.h>
#include <hip/hip_bf16.h>

// ---------------- problem constants (fixed by reference) ----------------
constexpr int NT = 4096;   // tokens = B*S = 2*2048
constexpr int DD = 768;    // model dim
constexpr int FF = 2048;   // ffn dim
constexpr int NE = 8;      // experts
constexpr int MAXROWS = 9216;   // 8192 + 8*127 rounded up to 128
constexpr int MAXMT128 = 72;    // MAXROWS/128
constexpr int MAXMT256 = 40;    // worst-case 256-row tiles (sum ceil(nt128_e/2))
constexpr int NKT1 = DD / 64;   // 12 K-tiles of 64 for gemm1
constexpr int NKT2 = FF / 64;   // 32 K-tiles of 64 for gemm2

// meta layout (int indices into ws[0..1024))
constexpr int IDX_CNTA   = 0;   // [8]  assignments per expert
constexpr int IDX_CNTT1  = 8;   // [8]  top-1 counts (load)
constexpr int IDX_CUR    = 16;  // [8]  scatter cursors
constexpr int IDX_IMP    = 24;  // [8]  float: sum of probs per expert
constexpr int IDX_ZSUM   = 32;  // float: sum logits^2
constexpr int IDX_NTILES = 33;
constexpr int IDX_OFF    = 34;  // [9]  128-aligned segment offsets
constexpr int IDX_EXPT   = 48;  // [MAXMT128] tile -> expert
constexpr int IDX_N256   = 120; // number of 256-row tiles
constexpr int IDX_E256   = 128; // [40] 256-tile -> expert
constexpr int IDX_B256   = 168; // [40] 256-tile -> base row
constexpr int IDX_L256   = 208; // [40] 256-tile -> row limit (segment end)

// ws byte offsets (all 256-aligned)
constexpr size_t OFF_META   = 0;
constexpr size_t OFF_TKE    = 1024;                           // int [NT][2]
constexpr size_t OFF_GATE   = OFF_TKE    + (size_t)NT*2*4;    // float [NT][2]
constexpr size_t OFF_ROWOF  = OFF_GATE   + (size_t)NT*2*4;    // (unused, keeps offsets)
constexpr size_t OFF_TOKROW = OFF_ROWOF  + (size_t)NT*2*4;    // int [MAXROWS]
constexpr size_t OFF_XG     = 136192;                              // bf16 [MAXROWS][DD]
constexpr size_t OFF_W1T    = OFF_XG  + (size_t)MAXROWS*DD*2;      // bf16 [NE][FF][DD]
constexpr size_t OFF_W3T    = OFF_W1T + (size_t)NE*FF*DD*2;
constexpr size_t OFF_W2T    = OFF_W3T + (size_t)NE*FF*DD*2;        // bf16 [NE][DD][FF]
constexpr size_t OFF_H      = OFF_W2T + (size_t)NE*FF*DD*2;        // bf16 [MAXROWS][FF]
constexpr size_t OFF_RGATE  = OFF_H   + (size_t)MAXROWS*FF*2;      // float [MAXROWS]

typedef float f32x4 __attribute__((ext_vector_type(4)));
typedef __bf16 bf16x8v __attribute__((ext_vector_type(8)));
typedef unsigned short u16x8 __attribute__((ext_vector_type(8)));

__device__ inline unsigned short f2bf_bits(float f) {
  __bf16 h = (__bf16)f;
  return *(unsigned short*)&h;
}

// async 16B global->LDS; LDS dest = wave-uniform base + lane*16 (m97/m104)
__device__ __forceinline__ void glds16(const void* g, void* l) {
  __builtin_amdgcn_global_load_lds(
      (const __attribute__((address_space(1))) unsigned int*)g,
      (__attribute__((address_space(3))) unsigned int*)l, 16, 0, 0);
}

// ---------------- router: fp32-exact logits, softmax, top-2 ----------------
constexpr int RB = 128;
__global__ __launch_bounds__(256) void router_kernel(const float* __restrict__ x,
    const float* __restrict__ rw, int* __restrict__ meta,
    int* __restrict__ tke, float* __restrict__ gateArr) {
  __shared__ float s_imp[NE];
  __shared__ float s_z;
  __shared__ int s_cnt1[NE], s_cnta[NE];
  if (threadIdx.x < NE) { s_imp[threadIdx.x] = 0.f; s_cnt1[threadIdx.x] = 0; s_cnta[threadIdx.x] = 0; }
  if (threadIdx.x == 0) s_z = 0.f;
  __syncthreads();

  const int wave = threadIdx.x >> 6, lane = threadIdx.x & 63;
  float impacc[NE];
  #pragma unroll
  for (int e = 0; e < NE; ++e) impacc[e] = 0.f;
  float zacc = 0.f;

  for (int t = blockIdx.x * 4 + wave; t < NT; t += RB * 4) {
    float acc[NE];
    #pragma unroll
    for (int e = 0; e < NE; ++e) acc[e] = 0.f;
    const float* xr = x + (size_t)t * DD;
    for (int i = lane; i < DD; i += 64) {
      float xv = xr[i];
      const float* r = rw + i * NE;
      #pragma unroll
      for (int e = 0; e < NE; ++e) acc[e] += xv * r[e];
    }
    #pragma unroll
    for (int off = 32; off > 0; off >>= 1) {
      #pragma unroll
      for (int e = 0; e < NE; ++e) acc[e] += __shfl_xor(acc[e], off);
    }
    float mx = acc[0];
    #pragma unroll
    for (int e = 1; e < NE; ++e) mx = fmaxf(mx, acc[e]);
    float p[NE]; float s = 0.f;
    #pragma unroll
    for (int e = 0; e < NE; ++e) { p[e] = __expf(acc[e] - mx); s += p[e]; }
    float inv = 1.f / s;
    #pragma unroll
    for (int e = 0; e < NE; ++e) p[e] *= inv;
    int e0 = 0; float p0 = p[0];
    #pragma unroll
    for (int e = 1; e < NE; ++e) if (p[e] > p0) { p0 = p[e]; e0 = e; }
    int e1 = -1; float p1 = -1.f;
    #pragma unroll
    for (int e = 0; e < NE; ++e) if (e != e0 && p[e] > p1) { p1 = p[e]; e1 = e; }
    if (lane == 0) {
      #pragma unroll
      for (int e = 0; e < NE; ++e) { impacc[e] += p[e]; zacc += acc[e] * acc[e]; }
      atomicAdd(&s_cnt1[e0], 1);
      atomicAdd(&s_cnta[e0], 1);
      atomicAdd(&s_cnta[e1], 1);
      float gs = 1.f / (p0 + p1);
      tke[t*2]   = e0; tke[t*2+1] = e1;
      gateArr[t*2] = p0 * gs; gateArr[t*2+1] = p1 * gs;
    }
  }
  if (lane == 0) {
    #pragma unroll
    for (int e = 0; e < NE; ++e) atomicAdd(&s_imp[e], impacc[e]);
    atomicAdd(&s_z, zacc);
  }
  __syncthreads();
  float* fmeta = (float*)meta;
  if (threadIdx.x < NE) {
    atomicAdd(&fmeta[IDX_IMP + threadIdx.x], s_imp[threadIdx.x]);
    atomicAdd(&meta[IDX_CNTT1 + threadIdx.x], s_cnt1[threadIdx.x]);
    atomicAdd(&meta[IDX_CNTA + threadIdx.x], s_cnta[threadIdx.x]);
  }
  if (threadIdx.x == NE) atomicAdd(&fmeta[IDX_ZSUM], s_z);
}

// ------------ scan (parallel): segment offsets + losses + 256-tile table --
__global__ __launch_bounds__(128) void scan_kernel(int* __restrict__ meta,
                                                   float* __restrict__ out_tail) {
  __shared__ int s_off[NE + 1];
  __shared__ int s_nt[NE];
  __shared__ float s_aux;
  const int t = threadIdx.x;
  if (t < NE) s_nt[t] = (meta[IDX_CNTA + t] + 127) >> 7;
  __syncthreads();
  if (t == 0) {
    int off = 0;
    for (int e = 0; e < NE; ++e) { s_off[e] = off; off += s_nt[e]; }
    s_off[NE] = off;
  }
  __syncthreads();
  const int ntiles = s_off[NE];
  if (t < NE) meta[IDX_OFF + t] = s_off[t] << 7;
  if (t == NE) { meta[IDX_OFF + NE] = ntiles << 7; meta[IDX_NTILES] = ntiles; }
  if (t < ntiles) {
    int e = 0;
    while (t >= s_off[e + 1]) e++;
    meta[IDX_EXPT + t] = e;
  }
  // 256-row tile table: pair consecutive 128-segments of an expert.
  if (t == 0) {
    int n2t = 0;
    for (int e = 0; e < NE; ++e) {
      const int base = s_off[e] << 7;
      const int lim  = base + (s_nt[e] << 7);
      const int n2 = (s_nt[e] + 1) >> 1;
      for (int i = 0; i < n2; ++i) {
        meta[IDX_E256 + n2t] = e;
        meta[IDX_B256 + n2t] = base + (i << 8);
        meta[IDX_L256 + n2t] = lim;
        ++n2t;
      }
    }
    meta[IDX_N256] = n2t;
  }
  float* fmeta = (float*)meta;
  float pl = 0.f;
  if (t < NE)
    pl = (fmeta[IDX_IMP + t] / (float)NT) * ((float)meta[IDX_CNTT1 + t] / (float)NT);
  if (t < 64) {
    #pragma unroll
    for (int off = 4; off > 0; off >>= 1) pl += __shfl_xor(pl, off);
    if (t == 0) s_aux = pl;
  }
  __syncthreads();
  if (t == 0) {
    out_tail[0] = (float)NE * s_aux * 0.01f;
    out_tail[1] = fmeta[IDX_ZSUM] / (float)(NT * NE) * 0.001f;
  }
}

// ---------------- scatter: block-chunked cursor reservation ---------------
// Emits tokrow + per-ROW gate (rowgate) for gemm2's fused combine.
__global__ __launch_bounds__(256) void scatter_kernel(const int* __restrict__ tke,
    int* __restrict__ meta, int* __restrict__ tokrow,
    float* __restrict__ rowgate, const float* __restrict__ gateArr) {
  __shared__ int s_cnt[NE], s_base[NE];
  const int t = blockIdx.x * 256 + threadIdx.x;
  if (threadIdx.x < NE) s_cnt[threadIdx.x] = 0;
  __syncthreads();
  const int e0 = tke[t*2], e1 = tke[t*2 + 1];
  const int l0 = atomicAdd(&s_cnt[e0], 1);
  const int l1 = atomicAdd(&s_cnt[e1], 1);
  __syncthreads();
  if (threadIdx.x < NE)
    s_base[threadIdx.x] = atomicAdd(&meta[IDX_CUR + threadIdx.x], s_cnt[threadIdx.x]);
  __syncthreads();
  const int r0 = meta[IDX_OFF + e0] + s_base[e0] + l0;
  const int r1 = meta[IDX_OFF + e1] + s_base[e1] + l1;
  tokrow[r0] = t;
  tokrow[r1] = t;
  rowgate[r0] = gateArr[t*2];
  rowgate[r1] = gateArr[t*2 + 1];
}

// ---------------- gather x rows -> bf16 Xg (zeros for padding) ------------
__global__ __launch_bounds__(192) void gather_kernel(const float* __restrict__ x,
    const int* __restrict__ tokrow, const int* __restrict__ meta,
    __bf16* __restrict__ Xg) {
  const int row = blockIdx.x;
  if (row >= meta[IDX_OFF + NE]) return;
  const int tok = tokrow[row];
  ushort4* dst = (ushort4*)(Xg + (size_t)row * DD);
  const int i = threadIdx.x;            // 192 threads x 4 elems = 768
  ushort4 o;
  if (tok >= 0) {
    float4 v = ((const float4*)(x + (size_t)tok * DD))[i];
    o.x = f2bf_bits(v.x); o.y = f2bf_bits(v.y);
    o.z = f2bf_bits(v.z); o.w = f2bf_bits(v.w);
  } else {
    o.x = o.y = o.z = o.w = 0;
  }
  dst[i] = o;
}

// ------------- transpose v3: float4 loads, b32 dual-column LDS reads ------
// pass 2 reworked: each thread handles a COLUMN PAIR via 8 x ds_read_b32
// (both bf16 unpacked from one dword) -> half the LDS instructions and
// conflicts of the old 16x ds_read_u16, single pass, 2 x 16B stores.
constexpr int TS = 68;
__global__ __launch_bounds__(256) void transpose_cvt_all(
    const float* __restrict__ w1, const float* __restrict__ w3,
    const float* __restrict__ w2, __bf16* __restrict__ W1t,
    __bf16* __restrict__ W3t, __bf16* __restrict__ W2t) {
  const int z = blockIdx.z, which = z >> 3, e = z & 7;
  const float* src; __bf16* dst; int R, C, rt, ct;
  if (which == 0)      { src = w1; dst = W1t; R = DD; C = FF; rt = blockIdx.y; ct = blockIdx.x; }
  else if (which == 1) { src = w3; dst = W3t; R = DD; C = FF; rt = blockIdx.y; ct = blockIdx.x; }
  else                 { src = w2; dst = W2t; R = FF; C = DD; rt = blockIdx.x; ct = blockIdx.y; }
  src += (size_t)e * DD * FF; dst += (size_t)e * DD * FF;
  const int r0 = rt * 64, c0 = ct * 64;
  __shared__ __align__(16) __bf16 tile[64 * TS];
  const int t = threadIdx.x;
  #pragma unroll
  for (int i = 0; i < 4; ++i) {                 // 1024 float4 = 64x64 fp32
    int idx = t + i * 256; int r = idx >> 4, q = idx & 15;
    float4 v = *(const float4*)&src[(size_t)(r0 + r) * C + c0 + q * 4];
    ushort4 o;
    o.x = f2bf_bits(v.x); o.y = f2bf_bits(v.y);
    o.z = f2bf_bits(v.z); o.w = f2bf_bits(v.w);
    *(ushort4*)&tile[r * TS + q * 4] = o;       // 8B-aligned (136r+8q)
  }
  __syncthreads();
  // pass 2 (single pass): cp = t>>3 covers cols {2cp, 2cp+1}; seg = t&7
  {
    const int cp = t >> 3, seg = t & 7;
    u16x8 oe, oo;
    #pragma unroll
    for (int k = 0; k < 8; ++k) {               // b32 read = 2 bf16 cols
      unsigned v = *(const unsigned*)&tile[(seg * 8 + k) * TS + cp * 2];
      oe[k] = (unsigned short)(v & 0xffffu);
      oo[k] = (unsigned short)(v >> 16);
    }
    *(u16x8*)&dst[(size_t)(c0 + cp * 2    ) * R + r0 + seg * 8] = oe;
    *(u16x8*)&dst[(size_t)(c0 + cp * 2 + 1) * R + r0 + seg * 8] = oo;
  }
}

// ---------------- gemm1: H = silu(Xg@W1e) * (Xg@W3e) ----------------------
// R1 version (best measured). 256x256 tile, BK=64, 8 waves, 4 phases/K-tile,
// counted vmcnt(8) boundary, read-side XOR swizzle via pre-swizzled source.
__global__ __launch_bounds__(512, 2) void gemm1_kernel(
    const __bf16* __restrict__ Xg, const __bf16* __restrict__ W1t,
    const __bf16* __restrict__ W3t, __bf16* __restrict__ Hb,
    const int* __restrict__ meta) {
  const int mt = blockIdx.y;
  if (mt >= meta[IDX_N256]) return;
  const int e      = meta[IDX_E256 + mt];
  const int m0     = meta[IDX_B256 + mt];
  const int rowlim = meta[IDX_L256 + mt];
  const int n0 = blockIdx.x * 128;           // F-columns [n0, n0+128)

  __shared__ __align__(16) __bf16 As[2][256 * 64];
  __shared__ __align__(16) __bf16 Bs[2][256 * 64];

  const int t = threadIdx.x, lane = t & 63, wid = t >> 6;
  const int wm = wid >> 2, wn = wid & 3;      // 2 x 4 wave grid
  const int lane15 = lane & 15, g = lane >> 4;

  const __bf16* __restrict__ W1e = W1t + (size_t)e * FF * DD;
  const __bf16* __restrict__ W3e = W3t + (size_t)e * FF * DD;

  const int aBase = (wm * 128 + lane15) * 64;
  const int bBase = (wn * 64 + lane15) * 64;
  const int c0 = ((g    ) ^ (lane & 7)) * 8;   // kk=0
  const int c1 = ((4 + g) ^ (lane & 7)) * 8;   // kk=1

  const int o0v = t, o1v = 512 + t;
  const int r0v = o0v >> 3, r1v = o1v >> 3;            // rows 0-63 / 64-127
  const int cl0 = (o0v & 7) ^ (r0v & 7), cl1 = (o1v & 7) ^ (r1v & 7);
  int gA00 = m0 + r0v;        if (gA00 >= MAXROWS) gA00 = 0;
  int gA01 = m0 + r1v;        if (gA01 >= MAXROWS) gA01 = 0;
  int gA10 = m0 + 128 + r0v;  if (gA10 >= MAXROWS) gA10 = 0;
  int gA11 = m0 + 128 + r1v;  if (gA11 >= MAXROWS) gA11 = 0;
  const __bf16* aS00 = Xg + (size_t)gA00 * DD + cl0 * 8;
  const __bf16* aS01 = Xg + (size_t)gA01 * DD + cl1 * 8;
  const __bf16* aS10 = Xg + (size_t)gA10 * DD + cl0 * 8;
  const __bf16* aS11 = Xg + (size_t)gA11 * DD + cl1 * 8;
  const int fc0 = n0 + ((r0v >> 5) << 4) + (r0v & 15);
  const int fc1 = n0 + ((r1v >> 5) << 4) + (r1v & 15);
  const __bf16* bW0 = (r0v & 16) ? W3e : W1e;
  const __bf16* bW1 = (r1v & 16) ? W3e : W1e;
  const __bf16* bS00 = bW0 + (size_t)fc0 * DD + cl0 * 8;
  const __bf16* bS01 = bW1 + (size_t)fc1 * DD + cl1 * 8;
  const __bf16* bS10 = bW0 + (size_t)(fc0 + 64) * DD + cl0 * 8;
  const __bf16* bS11 = bW1 + (size_t)(fc1 + 64) * DD + cl1 * 8;
  const int L00 = (       wid * 64) * 8;
  const int L01 = ( 512 + wid * 64) * 8;
  const int L10 = (1024 + wid * 64) * 8;
  const int L11 = (1536 + wid * 64) * 8;

  auto st2 = [&](__bf16* dstBuf, int kt, const __bf16* s0, const __bf16* s1,
                 int d0, int d1) {
    glds16(s0 + (size_t)kt * 64, dstBuf + d0);
    glds16(s1 + (size_t)kt * 64, dstBuf + d1);
  };

  const f32x4 zero = {0.f, 0.f, 0.f, 0.f};
  f32x4 acc[8][4];
  #pragma unroll
  for (int i = 0; i < 8; ++i)
    #pragma unroll
    for (int j = 0; j < 4; ++j) acc[i][j] = zero;

  __bf16 *Ac = &As[0][0], *An = &As[1][0];
  __bf16 *Bc = &Bs[0][0], *Bn = &Bs[1][0];

  st2(Ac, 0, aS00, aS01, L00, L01); st2(Ac, 0, aS10, aS11, L10, L11);
  st2(Bc, 0, bS00, bS01, L00, L01); st2(Bc, 0, bS10, bS11, L10, L11);
  st2(An, 1, aS00, aS01, L00, L01); st2(An, 1, aS10, aS11, L10, L11);
  st2(Bn, 1, bS00, bS01, L00, L01); st2(Bn, 1, bS10, bS11, L10, L11);
  asm volatile("s_waitcnt vmcnt(8)" ::: "memory");
  __builtin_amdgcn_s_barrier();

  bf16x8v af[8], ag[8], bf[8];

  for (int k = 0; k < NKT1; ++k) {
    const bool k2ok = (k < NKT1 - 2);
    // ---- P1: read A m0-3 (8) + ALL B (8); Q1 MFMA
    #pragma unroll
    for (int i = 0; i < 4; ++i) {
      af[i*2+0] = *(const bf16x8v*)&Ac[aBase + i*1024 + c0];
      af[i*2+1] = *(const bf16x8v*)&Ac[aBase + i*1024 + c1];
    }
    #pragma unroll
    for (int j = 0; j < 4; ++j) {
      bf[j*2+0] = *(const bf16x8v*)&Bc[bBase + j*1024 + c0];
      bf[j*2+1] = *(const bf16x8v*)&Bc[bBase + j*1024 + c1];
    }
    __builtin_amdgcn_s_barrier();
    asm volatile("s_waitcnt lgkmcnt(0)" ::: "memory");
    __builtin_amdgcn_s_setprio(1);
    #pragma unroll
    for (int i = 0; i < 4; ++i)
      #pragma unroll
      for (int j = 0; j < 2; ++j) {
        acc[i][j] = __builtin_amdgcn_mfma_f32_16x16x32_bf16(af[i*2+0], bf[j*2+0], acc[i][j], 0, 0, 0);
        acc[i][j] = __builtin_amdgcn_mfma_f32_16x16x32_bf16(af[i*2+1], bf[j*2+1], acc[i][j], 0, 0, 0);
      }
    __builtin_amdgcn_s_setprio(0);
    __builtin_amdgcn_s_barrier();   // end-P1: Bc fully consumed

    // ---- P2: read A m4-7 (8); stage B(k+2)-lo; Q2 MFMA
    #pragma unroll
    for (int i = 0; i < 4; ++i) {
      ag[i*2+0] = *(const bf16x8v*)&Ac[aBase + (4+i)*1024 + c0];
      ag[i*2+1] = *(const bf16x8v*)&Ac[aBase + (4+i)*1024 + c1];
    }
    if (k2ok) st2(Bc, k + 2, bS00, bS01, L00, L01);
    __builtin_amdgcn_s_barrier();
    asm volatile("s_waitcnt lgkmcnt(0)" ::: "memory");
    __builtin_amdgcn_s_setprio(1);
    #pragma unroll
    for (int i = 0; i < 4; ++i)
      #pragma unroll
      for (int j = 0; j < 2; ++j) {
        acc[4+i][j] = __builtin_amdgcn_mfma_f32_16x16x32_bf16(ag[i*2+0], bf[j*2+0], acc[4+i][j], 0, 0, 0);
        acc[4+i][j] = __builtin_amdgcn_mfma_f32_16x16x32_bf16(ag[i*2+1], bf[j*2+1], acc[4+i][j], 0, 0, 0);
      }
    __builtin_amdgcn_s_setprio(0);
    __builtin_amdgcn_s_barrier();   // end-P2: Ac fully consumed

    // ---- P3: stage A(k+2)-lo + B(k+2)-hi; Q3 MFMA
    if (k2ok) {
      st2(Ac, k + 2, aS00, aS01, L00, L01);
      st2(Bc, k + 2, bS10, bS11, L10, L11);
    }
    __builtin_amdgcn_s_barrier();
    __builtin_amdgcn_s_setprio(1);
    #pragma unroll
    for (int i = 0; i < 4; ++i)
      #pragma unroll
      for (int j = 0; j < 2; ++j) {
        acc[i][2+j] = __builtin_amdgcn_mfma_f32_16x16x32_bf16(af[i*2+0], bf[(2+j)*2+0], acc[i][2+j], 0, 0, 0);
        acc[i][2+j] = __builtin_amdgcn_mfma_f32_16x16x32_bf16(af[i*2+1], bf[(2+j)*2+1], acc[i][2+j], 0, 0, 0);
      }
    __builtin_amdgcn_s_setprio(0);
    __builtin_amdgcn_s_barrier();

    // ---- P4: stage A(k+2)-hi; Q4 MFMA; K-tile boundary sync
    if (k2ok) st2(Ac, k + 2, aS10, aS11, L10, L11);
    __builtin_amdgcn_s_barrier();
    __builtin_amdgcn_s_setprio(1);
    #pragma unroll
    for (int i = 0; i < 4; ++i)
      #pragma unroll
      for (int j = 0; j < 2; ++j) {
        acc[4+i][2+j] = __builtin_amdgcn_mfma_f32_16x16x32_bf16(ag[i*2+0], bf[(2+j)*2+0], acc[4+i][2+j], 0, 0, 0);
        acc[4+i][2+j] = __builtin_amdgcn_mfma_f32_16x16x32_bf16(ag[i*2+1], bf[(2+j)*2+1], acc[4+i][2+j], 0, 0, 0);
      }
    __builtin_amdgcn_s_setprio(0);
    if (k2ok)               { asm volatile("s_waitcnt vmcnt(8)" ::: "memory"); }
    else if (k == NKT1 - 2) { asm volatile("s_waitcnt vmcnt(0)" ::: "memory"); }
    __builtin_amdgcn_s_barrier();

    __bf16* tp;
    tp = Ac; Ac = An; An = tp;
    tp = Bc; Bc = Bn; Bn = tp;
  }

  // ---- epilogue: silu(c1)*c3 pairing is intra-lane (j=2p vs 2p+1)
  #pragma unroll
  for (int i = 0; i < 8; ++i) {
    const int grow = m0 + wm * 128 + i * 16 + (lane >> 4) * 4;
    #pragma unroll
    for (int p = 0; p < 2; ++p) {
      const int col = n0 + (wn * 2 + p) * 16 + lane15;
      const f32x4 v1 = acc[i][2*p], v3 = acc[i][2*p + 1];
      #pragma unroll
      for (int r = 0; r < 4; ++r) {
        if (grow + r < rowlim) {
          float h = v1[r] / (1.f + __expf(-v1[r])) * v3[r];
          Hb[(size_t)(grow + r) * FF + col] = (__bf16)h;
        }
      }
    }
  }
}

// ---------------- gemm2 + fused combine: out[tok] += g * (H @ W2e) --------
// 256M x 128N tile, BK=64, 8 waves, 2 phases/K-tile, K=2048 deep.
// Epilogue writes gate-weighted fp32 rows straight into out via atomicAdd
// (commutative fp32 add of exactly 2 contributions -> deterministic).
__global__ __launch_bounds__(512, 2) void gemm2_kernel(
    const __bf16* __restrict__ Hb, const __bf16* __restrict__ W2t,
    float* __restrict__ outp, const int* __restrict__ meta,
    const int* __restrict__ tokrow, const float* __restrict__ rowgate) {
  const int mt = blockIdx.y;
  if (mt >= meta[IDX_N256]) return;
  const int e      = meta[IDX_E256 + mt];
  const int m0     = meta[IDX_B256 + mt];
  const int rowlim = meta[IDX_L256 + mt];
  const int n0 = blockIdx.x * 128;           // D-columns [n0, n0+128)

  __shared__ __align__(16) __bf16 As[2][256 * 64];
  __shared__ __align__(16) __bf16 Bs[2][128 * 64];

  const int t = threadIdx.x, lane = t & 63, wid = t >> 6;
  const int wm = wid >> 2, wn = wid & 3;      // 2 x 4 wave grid
  const int lane15 = lane & 15, g = lane >> 4;

  const __bf16* __restrict__ W2e = W2t + (size_t)e * DD * FF;  // [DD][FF]

  const int aBase = (wm * 128 + lane15) * 64;
  const int bBase = (wn * 32 + lane15) * 64;
  const int c0 = ((g    ) ^ (lane & 7)) * 8;
  const int c1 = ((4 + g) ^ (lane & 7)) * 8;

  const int o0v = t, o1v = 512 + t;
  const int r0v = o0v >> 3, r1v = o1v >> 3;            // rows 0-63 / 64-127
  const int cl0 = (o0v & 7) ^ (r0v & 7), cl1 = (o1v & 7) ^ (r1v & 7);
  const int L00 = (       wid * 64) * 8;
  const int L01 = ( 512 + wid * 64) * 8;
  const int L10 = (1024 + wid * 64) * 8;
  const int L11 = (1536 + wid * 64) * 8;

  int gA00 = m0 + r0v;        if (gA00 >= MAXROWS) gA00 = 0;
  int gA01 = m0 + r1v;        if (gA01 >= MAXROWS) gA01 = 0;
  int gA10 = m0 + 128 + r0v;  if (gA10 >= MAXROWS) gA10 = 0;
  int gA11 = m0 + 128 + r1v;  if (gA11 >= MAXROWS) gA11 = 0;
  const __bf16* aS00 = Hb + (size_t)gA00 * FF + cl0 * 8;
  const __bf16* aS01 = Hb + (size_t)gA01 * FF + cl1 * 8;
  const __bf16* aS10 = Hb + (size_t)gA10 * FF + cl0 * 8;
  const __bf16* aS11 = Hb + (size_t)gA11 * FF + cl1 * 8;
  const __bf16* bS0  = W2e + (size_t)(n0 + r0v) * FF + cl0 * 8;  // 128 B rows
  const __bf16* bS1  = W2e + (size_t)(n0 + r1v) * FF + cl1 * 8;

  auto stA = [&](__bf16* d, int kt) {
    glds16(aS00 + (size_t)kt * 64, d + L00);
    glds16(aS01 + (size_t)kt * 64, d + L01);
    glds16(aS10 + (size_t)kt * 64, d + L10);
    glds16(aS11 + (size_t)kt * 64, d + L11);
  };
  auto stB = [&](__bf16* d, int kt) {
    glds16(bS0 + (size_t)kt * 64, d + L00);
    glds16(bS1 + (size_t)kt * 64, d + L01);
  };

  const f32x4 zero = {0.f, 0.f, 0.f, 0.f};
  f32x4 acc[8][2];
  #pragma unroll
  for (int i = 0; i < 8; ++i)
    #pragma unroll
    for (int j = 0; j < 2; ++j) acc[i][j] = zero;

  __bf16 *Ac = &As[0][0], *An = &As[1][0];
  __bf16 *Bc = &Bs[0][0], *Bn = &Bs[1][0];

  stA(Ac, 0); stB(Bc, 0);
  stA(An, 1); stB(Bn, 1);
  asm volatile("s_waitcnt vmcnt(6)" ::: "memory");
  __builtin_amdgcn_s_barrier();

  bf16x8v af[8], ag[8], bfr[4];

  for (int k = 0; k < NKT2; ++k) {
    const bool k2ok = (k < NKT2 - 2);
    // ---- P1: read ALL frags (20); Q1 MFMA (af x b)
    #pragma unroll
    for (int i = 0; i < 4; ++i) {
      af[i*2+0] = *(const bf16x8v*)&Ac[aBase + i*1024 + c0];
      af[i*2+1] = *(const bf16x8v*)&Ac[aBase + i*1024 + c1];
    }
    #pragma unroll
    for (int i = 0; i < 4; ++i) {
      ag[i*2+0] = *(const bf16x8v*)&Ac[aBase + (4+i)*1024 + c0];
      ag[i*2+1] = *(const bf16x8v*)&Ac[aBase + (4+i)*1024 + c1];
    }
    #pragma unroll
    for (int j = 0; j < 2; ++j) {
      bfr[j*2+0] = *(const bf16x8v*)&Bc[bBase + j*1024 + c0];
      bfr[j*2+1] = *(const bf16x8v*)&Bc[bBase + j*1024 + c1];
    }
    __builtin_amdgcn_s_barrier();
    asm volatile("s_waitcnt lgkmcnt(0)" ::: "memory");
    __builtin_amdgcn_s_setprio(1);
    #pragma unroll
    for (int i = 0; i < 4; ++i)
      #pragma unroll
      for (int j = 0; j < 2; ++j) {
        acc[i][j] = __builtin_amdgcn_mfma_f32_16x16x32_bf16(af[i*2+0], bfr[j*2+0], acc[i][j], 0, 0, 0);
        acc[i][j] = __builtin_amdgcn_mfma_f32_16x16x32_bf16(af[i*2+1], bfr[j*2+1], acc[i][j], 0, 0, 0);
      }
    __builtin_amdgcn_s_setprio(0);
    __builtin_amdgcn_s_barrier();   // end-P1: all LDS reads of tile k done

    // ---- P2: stage tile k+2 (6 glds); Q2 MFMA (ag x b); boundary
    if (k2ok) { stA(Ac, k + 2); stB(Bc, k + 2); }
    __builtin_amdgcn_s_setprio(1);
    #pragma unroll
    for (int i = 0; i < 4; ++i)
      #pragma unroll
      for (int j = 0; j < 2; ++j) {
        acc[4+i][j] = __builtin_amdgcn_mfma_f32_16x16x32_bf16(ag[i*2+0], bfr[j*2+0], acc[4+i][j], 0, 0, 0);
        acc[4+i][j] = __builtin_amdgcn_mfma_f32_16x16x32_bf16(ag[i*2+1], bfr[j*2+1], acc[4+i][j], 0, 0, 0);
      }
    __builtin_amdgcn_s_setprio(0);
    if (k2ok)               { asm volatile("s_waitcnt vmcnt(6)" ::: "memory"); }
    else if (k == NKT2 - 2) { asm volatile("s_waitcnt vmcnt(0)" ::: "memory"); }
    __builtin_amdgcn_s_barrier();

    __bf16* tp;
    tp = Ac; Ac = An; An = tp;
    tp = Bc; Bc = Bn; Bn = tp;
  }

  // ---- fused combine epilogue: out[tok] += gate * acc (fp32 atomics)
  #pragma unroll
  for (int i = 0; i < 8; ++i) {
    const int rowb = m0 + wm * 128 + i * 16 + (lane >> 4) * 4;
    #pragma unroll
    for (int r = 0; r < 4; ++r) {
      const int row = rowb + r;
      if (row < rowlim) {
        const int tok = tokrow[row];
        if (tok >= 0) {
          const float gv = rowgate[row];
          #pragma unroll
          for (int jj = 0; jj < 2; ++jj) {
            const int col = n0 + wn * 32 + jj * 16 + lane15;
            atomicAdd(&outp[(size_t)tok * DD + col], gv * acc[i][jj][r]);
          }
        }
      }
    }
  }
}

extern "C" void kernel_launch(void* const* d_in, const int* in_sizes, int n_in,
                              void* d_out, int out_size, void* d_ws, size_t ws_size,
                              hipStream_t stream) {
  const float* x  = (const float*)d_in[0];
  const float* rw = (const float*)d_in[1];
  const float* w1 = (const float*)d_in[2];
  const float* w2 = (const float*)d_in[3];
  const float* w3 = (const float*)d_in[4];
  float* out = (float*)d_out;

  char* ws = (char*)d_ws;
  int*    meta   = (int*)(ws + OFF_META);
  int*    tke    = (int*)(ws + OFF_TKE);
  float*  gateA  = (float*)(ws + OFF_GATE);
  int*    tokrow = (int*)(ws + OFF_TOKROW);
  __bf16* Xg     = (__bf16*)(ws + OFF_XG);
  __bf16* W1t    = (__bf16*)(ws + OFF_W1T);
  __bf16* W3t    = (__bf16*)(ws + OFF_W3T);
  __bf16* W2t    = (__bf16*)(ws + OFF_W2T);
  __bf16* Hb     = (__bf16*)(ws + OFF_H);
  float*  rgate  = (float*)(ws + OFF_RGATE);

  hipMemsetAsync(ws + OFF_META, 0, 1024, stream);
  hipMemsetAsync(ws + OFF_TOKROW, 0xFF, (size_t)MAXROWS * 4, stream);  // tok=-1
  hipMemsetAsync(out, 0, (size_t)NT * DD * 4, stream);                 // combine base

  transpose_cvt_all<<<dim3(32, 12, 24), 256, 0, stream>>>(w1, w3, w2, W1t, W3t, W2t);

  router_kernel<<<RB, 256, 0, stream>>>(x, rw, meta, tke, gateA);
  scan_kernel<<<1, 128, 0, stream>>>(meta, out + (size_t)NT * DD);
  scatter_kernel<<<NT/256, 256, 0, stream>>>(tke, meta, tokrow, rgate, gateA);
  gather_kernel<<<MAXROWS, 192, 0, stream>>>(x, tokrow, meta, Xg);

  gemm1_kernel<<<dim3(FF/128, MAXMT256), 512, 0, stream>>>(Xg, W1t, W3t, Hb, meta);
  gemm2_kernel<<<dim3(DD/128, MAXMT256), 512, 0, stream>>>(Hb, W2t, out, meta,
                                                           tokrow, rgate);
}

// Round 7
// 352.884 us; speedup vs baseline: 1.1925x; 1.1925x over previous
//
#include <hip/hip_runtime.h>
#include <hip/hip_bf16.h>

// ---------------- problem constants (fixed by reference) ----------------
constexpr int NT = 4096;   // tokens = B*S = 2*2048
constexpr int DD = 768;    // model dim
constexpr int FF = 2048;   // ffn dim
constexpr int NE = 8;      // experts
constexpr int MAXROWS = 9216;   // 8192 + 8*127 rounded up to 128
constexpr int MAXMT128 = 72;    // MAXROWS/128

// meta layout (int indices into ws[0..1024))
constexpr int IDX_CNTA   = 0;   // [8]  assignments per expert
constexpr int IDX_CNTT1  = 8;   // [8]  top-1 counts (load)
constexpr int IDX_CUR    = 16;  // [8]  scatter cursors
constexpr int IDX_IMP    = 24;  // [8]  float: sum of probs per expert
constexpr int IDX_ZSUM   = 32;  // float: sum logits^2
constexpr int IDX_NTILES = 33;
constexpr int IDX_OFF    = 34;  // [9]  128-aligned segment offsets
constexpr int IDX_EXPT   = 48;  // [MAXMT128] tile -> expert

// ws byte offsets (all 256-aligned)
constexpr size_t OFF_META   = 0;
constexpr size_t OFF_TKE    = 1024;                           // int [NT][2]
constexpr size_t OFF_GATE   = OFF_TKE    + (size_t)NT*2*4;    // float [NT][2]
constexpr size_t OFF_ROWOF  = OFF_GATE   + (size_t)NT*2*4;    // int [NT][2]
constexpr size_t OFF_TOKROW = OFF_ROWOF  + (size_t)NT*2*4;    // int [MAXROWS]
constexpr size_t OFF_XG     = 136192;                              // bf16 [MAXROWS][DD]
constexpr size_t OFF_W1T    = OFF_XG  + (size_t)MAXROWS*DD*2;      // bf16 [NE][FF][DD]
constexpr size_t OFF_W3T    = OFF_W1T + (size_t)NE*FF*DD*2;
constexpr size_t OFF_W2T    = OFF_W3T + (size_t)NE*FF*DD*2;        // bf16 [NE][DD][FF]
constexpr size_t OFF_H      = OFF_W2T + (size_t)NE*FF*DD*2;        // bf16 [MAXROWS][FF]
constexpr size_t OFF_OP     = OFF_H   + (size_t)MAXROWS*FF*2;      // bf16 [MAXROWS][DD]

typedef float f32x4 __attribute__((ext_vector_type(4)));
typedef __bf16 bf16x8v __attribute__((ext_vector_type(8)));
typedef unsigned short u16x8 __attribute__((ext_vector_type(8)));

__device__ inline unsigned short f2bf_bits(float f) {
  __bf16 h = (__bf16)f;
  return *(unsigned short*)&h;
}
__device__ inline float bf2f(unsigned short u) {
  unsigned v = (unsigned)u << 16;
  return *(float*)&v;
}

// async 16B global->LDS; LDS dest = wave-uniform base + lane*16 (m97/m104)
__device__ __forceinline__ void glds16(const void* g, void* l) {
  __builtin_amdgcn_global_load_lds(
      (const __attribute__((address_space(1))) unsigned int*)g,
      (__attribute__((address_space(3))) unsigned int*)l, 16, 0, 0);
}

// ---------------- router: fp32-exact logits, softmax, top-2 ----------------
// v2: float4 x-loads (3 iters instead of 12 scalar); also initializes
// tokrow[0..MAXROWS) = -1, replacing the 0xFF memset launch (stream order
// guarantees completion before scatter/gather read it).
constexpr int RB = 128;
__global__ __launch_bounds__(256) void router_kernel(const float* __restrict__ x,
    const float* __restrict__ rw, int* __restrict__ meta,
    int* __restrict__ tke, float* __restrict__ gateArr,
    int* __restrict__ tokrow) {
  const int gtid = blockIdx.x * 256 + threadIdx.x;
  if (gtid < MAXROWS) tokrow[gtid] = -1;     // folded memset (tok = -1)

  __shared__ float s_imp[NE];
  __shared__ float s_z;
  __shared__ int s_cnt1[NE], s_cnta[NE];
  if (threadIdx.x < NE) { s_imp[threadIdx.x] = 0.f; s_cnt1[threadIdx.x] = 0; s_cnta[threadIdx.x] = 0; }
  if (threadIdx.x == 0) s_z = 0.f;
  __syncthreads();

  const int wave = threadIdx.x >> 6, lane = threadIdx.x & 63;
  float impacc[NE];
  #pragma unroll
  for (int e = 0; e < NE; ++e) impacc[e] = 0.f;
  float zacc = 0.f;

  for (int t = blockIdx.x * 4 + wave; t < NT; t += RB * 4) {
    float acc[NE];
    #pragma unroll
    for (int e = 0; e < NE; ++e) acc[e] = 0.f;
    const float* xr = x + (size_t)t * DD;
    for (int i = lane; i < DD / 4; i += 64) {     // 192/64 = 3 iters, float4
      float4 xv = ((const float4*)xr)[i];
      const float* r = rw + i * 4 * NE;
      #pragma unroll
      for (int e = 0; e < NE; ++e) acc[e] += xv.x * r[e];
      #pragma unroll
      for (int e = 0; e < NE; ++e) acc[e] += xv.y * r[NE + e];
      #pragma unroll
      for (int e = 0; e < NE; ++e) acc[e] += xv.z * r[2*NE + e];
      #pragma unroll
      for (int e = 0; e < NE; ++e) acc[e] += xv.w * r[3*NE + e];
    }
    #pragma unroll
    for (int off = 32; off > 0; off >>= 1) {
      #pragma unroll
      for (int e = 0; e < NE; ++e) acc[e] += __shfl_xor(acc[e], off);
    }
    float mx = acc[0];
    #pragma unroll
    for (int e = 1; e < NE; ++e) mx = fmaxf(mx, acc[e]);
    float p[NE]; float s = 0.f;
    #pragma unroll
    for (int e = 0; e < NE; ++e) { p[e] = __expf(acc[e] - mx); s += p[e]; }
    float inv = 1.f / s;
    #pragma unroll
    for (int e = 0; e < NE; ++e) p[e] *= inv;
    int e0 = 0; float p0 = p[0];
    #pragma unroll
    for (int e = 1; e < NE; ++e) if (p[e] > p0) { p0 = p[e]; e0 = e; }
    int e1 = -1; float p1 = -1.f;
    #pragma unroll
    for (int e = 0; e < NE; ++e) if (e != e0 && p[e] > p1) { p1 = p[e]; e1 = e; }
    if (lane == 0) {
      #pragma unroll
      for (int e = 0; e < NE; ++e) { impacc[e] += p[e]; zacc += acc[e] * acc[e]; }
      atomicAdd(&s_cnt1[e0], 1);
      atomicAdd(&s_cnta[e0], 1);
      atomicAdd(&s_cnta[e1], 1);
      float gs = 1.f / (p0 + p1);
      tke[t*2]   = e0; tke[t*2+1] = e1;
      gateArr[t*2] = p0 * gs; gateArr[t*2+1] = p1 * gs;
    }
  }
  if (lane == 0) {
    #pragma unroll
    for (int e = 0; e < NE; ++e) atomicAdd(&s_imp[e], impacc[e]);
    atomicAdd(&s_z, zacc);
  }
  __syncthreads();
  float* fmeta = (float*)meta;
  if (threadIdx.x < NE) {
    atomicAdd(&fmeta[IDX_IMP + threadIdx.x], s_imp[threadIdx.x]);
    atomicAdd(&meta[IDX_CNTT1 + threadIdx.x], s_cnt1[threadIdx.x]);
    atomicAdd(&meta[IDX_CNTA + threadIdx.x], s_cnta[threadIdx.x]);
  }
  if (threadIdx.x == NE) atomicAdd(&fmeta[IDX_ZSUM], s_z);
}

// ------------ scan (parallel): segment offsets + losses -------------------
__global__ __launch_bounds__(128) void scan_kernel(int* __restrict__ meta,
                                                   float* __restrict__ out_tail) {
  __shared__ int s_off[NE + 1];
  __shared__ int s_nt[NE];
  __shared__ float s_aux;
  const int t = threadIdx.x;
  if (t < NE) s_nt[t] = (meta[IDX_CNTA + t] + 127) >> 7;
  __syncthreads();
  if (t == 0) {
    int off = 0;
    for (int e = 0; e < NE; ++e) { s_off[e] = off; off += s_nt[e]; }
    s_off[NE] = off;
  }
  __syncthreads();
  const int ntiles = s_off[NE];
  if (t < NE) meta[IDX_OFF + t] = s_off[t] << 7;
  if (t == NE) { meta[IDX_OFF + NE] = ntiles << 7; meta[IDX_NTILES] = ntiles; }
  if (t < ntiles) {
    int e = 0;
    while (t >= s_off[e + 1]) e++;
    meta[IDX_EXPT + t] = e;
  }
  float* fmeta = (float*)meta;
  float pl = 0.f;
  if (t < NE)
    pl = (fmeta[IDX_IMP + t] / (float)NT) * ((float)meta[IDX_CNTT1 + t] / (float)NT);
  if (t < 64) {
    #pragma unroll
    for (int off = 4; off > 0; off >>= 1) pl += __shfl_xor(pl, off);
    if (t == 0) s_aux = pl;
  }
  __syncthreads();
  if (t == 0) {
    out_tail[0] = (float)NE * s_aux * 0.01f;
    out_tail[1] = fmeta[IDX_ZSUM] / (float)(NT * NE) * 0.001f;
  }
}

// ---------------- scatter: block-chunked cursor reservation ---------------
__global__ __launch_bounds__(256) void scatter_kernel(const int* __restrict__ tke,
    int* __restrict__ meta, int* __restrict__ rowof, int* __restrict__ tokrow) {
  __shared__ int s_cnt[NE], s_base[NE];
  const int t = blockIdx.x * 256 + threadIdx.x;
  if (threadIdx.x < NE) s_cnt[threadIdx.x] = 0;
  __syncthreads();
  const int e0 = tke[t*2], e1 = tke[t*2 + 1];
  const int l0 = atomicAdd(&s_cnt[e0], 1);
  const int l1 = atomicAdd(&s_cnt[e1], 1);
  __syncthreads();
  if (threadIdx.x < NE)
    s_base[threadIdx.x] = atomicAdd(&meta[IDX_CUR + threadIdx.x], s_cnt[threadIdx.x]);
  __syncthreads();
  const int r0 = meta[IDX_OFF + e0] + s_base[e0] + l0;
  const int r1 = meta[IDX_OFF + e1] + s_base[e1] + l1;
  rowof[t*2]     = r0;
  rowof[t*2 + 1] = r1;
  tokrow[r0] = t;
  tokrow[r1] = t;
}

// ---------------- gather x rows -> bf16 Xg (zeros for padding) ------------
__global__ __launch_bounds__(192) void gather_kernel(const float* __restrict__ x,
    const int* __restrict__ tokrow, const int* __restrict__ meta,
    __bf16* __restrict__ Xg) {
  const int row = blockIdx.x;
  if (row >= meta[IDX_OFF + NE]) return;
  const int tok = tokrow[row];
  ushort4* dst = (ushort4*)(Xg + (size_t)row * DD);
  const int i = threadIdx.x;            // 192 threads x 4 elems = 768
  ushort4 o;
  if (tok >= 0) {
    float4 v = ((const float4*)(x + (size_t)tok * DD))[i];
    o.x = f2bf_bits(v.x); o.y = f2bf_bits(v.y);
    o.z = f2bf_bits(v.z); o.w = f2bf_bits(v.w);
  } else {
    o.x = o.y = o.z = o.w = 0;
  }
  dst[i] = o;
}

// ------------- transpose v4: 2 tiles/block, all loads issued up front -----
// Pipelines tile B's HBM latency under tile A's LDS phase; halves block
// count (grid 16x12x24). Pass-2 identical to R0's verified v2. Block
// (0,0,0) zeroes meta (replaces memset launch; router runs after in
// stream order).
constexpr int TS = 68;
__global__ __launch_bounds__(256) void transpose_cvt_all(
    const float* __restrict__ w1, const float* __restrict__ w3,
    const float* __restrict__ w2, __bf16* __restrict__ W1t,
    __bf16* __restrict__ W3t, __bf16* __restrict__ W2t,
    int* __restrict__ meta) {
  if (blockIdx.x == 0 && blockIdx.y == 0 && blockIdx.z == 0)
    meta[threadIdx.x] = 0;                        // 256 ints = full meta page

  const int z = blockIdx.z, which = z >> 3, e = z & 7;
  const float* src; __bf16* dst; int R, C;
  int r0a, c0a, r0b, c0b;
  if (which == 0)      { src = w1; dst = W1t; R = DD; C = FF;
                         r0a = blockIdx.y * 64; c0a = blockIdx.x * 128;
                         r0b = r0a;             c0b = c0a + 64; }
  else if (which == 1) { src = w3; dst = W3t; R = DD; C = FF;
                         r0a = blockIdx.y * 64; c0a = blockIdx.x * 128;
                         r0b = r0a;             c0b = c0a + 64; }
  else                 { src = w2; dst = W2t; R = FF; C = DD;
                         r0a = blockIdx.x * 128; c0a = blockIdx.y * 64;
                         r0b = r0a + 64;         c0b = c0a; }
  src += (size_t)e * DD * FF; dst += (size_t)e * DD * FF;
  __shared__ __align__(16) __bf16 tile[64 * TS];
  const int t = threadIdx.x;
  const int rr = t >> 4, qq = t & 15;             // thread's (row, quad) slot

  // ---- issue ALL 8 global loads first (2 tiles x 4 rounds) ----
  float4 va[4], vb[4];
  #pragma unroll
  for (int i = 0; i < 4; ++i)
    va[i] = *(const float4*)&src[(size_t)(r0a + rr + i * 16) * C + c0a + qq * 4];
  #pragma unroll
  for (int i = 0; i < 4; ++i)
    vb[i] = *(const float4*)&src[(size_t)(r0b + rr + i * 16) * C + c0b + qq * 4];

  // ---- tile A: cvt -> LDS -> transpose-store ----
  #pragma unroll
  for (int i = 0; i < 4; ++i) {
    ushort4 o;
    o.x = f2bf_bits(va[i].x); o.y = f2bf_bits(va[i].y);
    o.z = f2bf_bits(va[i].z); o.w = f2bf_bits(va[i].w);
    *(ushort4*)&tile[(rr + i * 16) * TS + qq * 4] = o;   // 8B-aligned
  }
  __syncthreads();
  #pragma unroll
  for (int i = 0; i < 2; ++i) {                 // 512 ushort8 = 64x64 bf16
    int idx = t + i * 256; int c = idx >> 3, seg = idx & 7;
    u16x8 o;
    #pragma unroll
    for (int k = 0; k < 8; ++k)
      o[k] = *(unsigned short*)&tile[(seg * 8 + k) * TS + c];
    *(u16x8*)&dst[(size_t)(c0a + c) * R + r0a + seg * 8] = o;
  }
  __syncthreads();

  // ---- tile B: cvt -> LDS -> transpose-store ----
  #pragma unroll
  for (int i = 0; i < 4; ++i) {
    ushort4 o;
    o.x = f2bf_bits(vb[i].x); o.y = f2bf_bits(vb[i].y);
    o.z = f2bf_bits(vb[i].z); o.w = f2bf_bits(vb[i].w);
    *(ushort4*)&tile[(rr + i * 16) * TS + qq * 4] = o;
  }
  __syncthreads();
  #pragma unroll
  for (int i = 0; i < 2; ++i) {
    int idx = t + i * 256; int c = idx >> 3, seg = idx & 7;
    u16x8 o;
    #pragma unroll
    for (int k = 0; k < 8; ++k)
      o[k] = *(unsigned short*)&tile[(seg * 8 + k) * TS + c];
    *(u16x8*)&dst[(size_t)(c0b + c) * R + r0b + seg * 8] = o;
  }
}

// ---------------- gemm1: H = silu(Xg@W1e) * (Xg@W3e) ----------------------
// R0 version verbatim (twice-measured 378us-total anchor).
__global__ __launch_bounds__(256) void gemm1_kernel(const __bf16* __restrict__ Xg,
    const __bf16* __restrict__ W1t, const __bf16* __restrict__ W3t,
    __bf16* __restrict__ Hb, const int* __restrict__ meta) {
  const int mt = blockIdx.y;
  if (mt >= meta[IDX_NTILES]) return;
  const int e = meta[IDX_EXPT + mt];
  const int n0 = blockIdx.x * 64;
  const int m0 = mt * 128;
  __shared__ __align__(16) __bf16 As[128*32], B1s[64*32], B3s[64*32];
  const int t = threadIdx.x, wave = t >> 6, lane = t & 63;
  const __bf16* w1e = W1t + (size_t)e * FF * DD;  // [FF][DD]
  const __bf16* w3e = W3t + (size_t)e * FF * DD;
  const f32x4 zero = {0.f, 0.f, 0.f, 0.f};
  f32x4 acc1[2][4], acc3[2][4];
  #pragma unroll
  for (int i = 0; i < 2; ++i)
    #pragma unroll
    for (int j = 0; j < 4; ++j) { acc1[i][j] = zero; acc3[i][j] = zero; }

  const __bf16* gA  = Xg  + (size_t)(m0 + 32*wave + (lane >> 2)) * DD + (lane & 3) * 8;
  const __bf16* gB1 = w1e + (size_t)(n0 + 16*wave + (lane >> 2)) * DD + (lane & 3) * 8;
  const __bf16* gB3 = w3e + (size_t)(n0 + 16*wave + (lane >> 2)) * DD + (lane & 3) * 8;
  __bf16* lA0 = &As [(32*wave     ) * 32];
  __bf16* lA1 = &As [(32*wave + 16) * 32];
  __bf16* lB1 = &B1s[(16*wave     ) * 32];
  __bf16* lB3 = &B3s[(16*wave     ) * 32];

  for (int k0 = 0; k0 < DD; k0 += 32) {
    glds16(gA  + k0,           lA0);
    glds16(gA  + k0 + 16*DD,   lA1);
    glds16(gB1 + k0,           lB1);
    glds16(gB3 + k0,           lB3);
    __syncthreads();
    bf16x8v a[2], b1[4], b3[4];
    #pragma unroll
    for (int i = 0; i < 2; ++i)
      a[i] = *(const bf16x8v*)&As[(32*wave + 16*i + (lane & 15))*32 + (lane >> 4)*8];
    #pragma unroll
    for (int j = 0; j < 4; ++j) {
      b1[j] = *(const bf16x8v*)&B1s[(16*j + (lane & 15))*32 + (lane >> 4)*8];
      b3[j] = *(const bf16x8v*)&B3s[(16*j + (lane & 15))*32 + (lane >> 4)*8];
    }
    #pragma unroll
    for (int i = 0; i < 2; ++i)
      #pragma unroll
      for (int j = 0; j < 4; ++j) {
        acc1[i][j] = __builtin_amdgcn_mfma_f32_16x16x32_bf16(a[i], b1[j], acc1[i][j], 0, 0, 0);
        acc3[i][j] = __builtin_amdgcn_mfma_f32_16x16x32_bf16(a[i], b3[j], acc3[i][j], 0, 0, 0);
      }
    __syncthreads();
  }
  #pragma unroll
  for (int i = 0; i < 2; ++i) {
    const int rowb = m0 + 32*wave + 16*i + (lane >> 4)*4;
    #pragma unroll
    for (int j = 0; j < 4; ++j) {
      const int col = n0 + 16*j + (lane & 15);
      #pragma unroll
      for (int r = 0; r < 4; ++r) {
        float c1 = acc1[i][j][r], c3 = acc3[i][j][r];
        float h = c1 / (1.f + __expf(-c1)) * c3;   // silu(c1)*c3
        Hb[(size_t)(rowb + r)*FF + col] = (__bf16)h;
      }
    }
  }
}

// ---------------- gemm2: OP = H @ W2e; 128x128 m97-style ------------------
// R0 version verbatim.
__global__ __launch_bounds__(256) void gemm2_kernel(const __bf16* __restrict__ Hb,
    const __bf16* __restrict__ W2t, __bf16* __restrict__ OP,
    const int* __restrict__ meta) {
  const int mt = blockIdx.y;
  if (mt >= meta[IDX_NTILES]) return;
  const int e = meta[IDX_EXPT + mt];
  const int n0 = blockIdx.x * 128;
  const int m0 = mt * 128;
  __shared__ __align__(16) __bf16 As[128*32], Bs[128*32];
  const int t = threadIdx.x, wave = t >> 6, lane = t & 63;
  const int wm = wave & 1, wn = wave >> 1;
  const __bf16* w2e = W2t + (size_t)e * DD * FF;  // [DD][FF]
  const f32x4 zero = {0.f, 0.f, 0.f, 0.f};
  f32x4 acc[4][4];
  #pragma unroll
  for (int i = 0; i < 4; ++i)
    #pragma unroll
    for (int j = 0; j < 4; ++j) acc[i][j] = zero;

  const __bf16* gA = Hb  + (size_t)(m0 + 32*wave + (lane >> 2)) * FF + (lane & 3) * 8;
  const __bf16* gB = w2e + (size_t)(n0 + 32*wave + (lane >> 2)) * FF + (lane & 3) * 8;
  __bf16* lA0 = &As[(32*wave     ) * 32];
  __bf16* lA1 = &As[(32*wave + 16) * 32];
  __bf16* lB0 = &Bs[(32*wave     ) * 32];
  __bf16* lB1 = &Bs[(32*wave + 16) * 32];

  for (int k0 = 0; k0 < FF; k0 += 32) {
    glds16(gA + k0,          lA0);
    glds16(gA + k0 + 16*FF,  lA1);
    glds16(gB + k0,          lB0);
    glds16(gB + k0 + 16*FF,  lB1);
    __syncthreads();
    bf16x8v a[4], b[4];
    #pragma unroll
    for (int i = 0; i < 4; ++i) {
      a[i] = *(const bf16x8v*)&As[(64*wm + 16*i + (lane & 15))*32 + (lane >> 4)*8];
      b[i] = *(const bf16x8v*)&Bs[(64*wn + 16*i + (lane & 15))*32 + (lane >> 4)*8];
    }
    #pragma unroll
    for (int i = 0; i < 4; ++i)
      #pragma unroll
      for (int j = 0; j < 4; ++j)
        acc[i][j] = __builtin_amdgcn_mfma_f32_16x16x32_bf16(a[i], b[j], acc[i][j], 0, 0, 0);
    __syncthreads();
  }
  #pragma unroll
  for (int i = 0; i < 4; ++i) {
    const int rowb = m0 + 64*wm + 16*i + (lane >> 4)*4;
    #pragma unroll
    for (int j = 0; j < 4; ++j) {
      const int col = n0 + 64*wn + 16*j + (lane & 15);
      #pragma unroll
      for (int r = 0; r < 4; ++r)
        OP[(size_t)(rowb + r)*DD + col] = (__bf16)acc[i][j][r];
    }
  }
}

// ---------------- combine: out[t] = g0*OP[row0] + g1*OP[row1] -------------
__global__ __launch_bounds__(192) void combine_kernel(const __bf16* __restrict__ OP,
    const int* __restrict__ rowof, const float* __restrict__ gateArr,
    float* __restrict__ out) {
  const int t = blockIdx.x;
  const int r0 = rowof[t*2], r1 = rowof[t*2 + 1];
  const float g0 = gateArr[t*2], g1 = gateArr[t*2 + 1];
  const ushort4* p0 = (const ushort4*)(OP + (size_t)r0 * DD);
  const ushort4* p1 = (const ushort4*)(OP + (size_t)r1 * DD);
  const int i = threadIdx.x;
  ushort4 a = p0[i], b = p1[i];
  float4 o;
  o.x = g0 * bf2f(a.x) + g1 * bf2f(b.x);
  o.y = g0 * bf2f(a.y) + g1 * bf2f(b.y);
  o.z = g0 * bf2f(a.z) + g1 * bf2f(b.z);
  o.w = g0 * bf2f(a.w) + g1 * bf2f(b.w);
  ((float4*)(out + (size_t)t * DD))[i] = o;
}

extern "C" void kernel_launch(void* const* d_in, const int* in_sizes, int n_in,
                              void* d_out, int out_size, void* d_ws, size_t ws_size,
                              hipStream_t stream) {
  const float* x  = (const float*)d_in[0];
  const float* rw = (const float*)d_in[1];
  const float* w1 = (const float*)d_in[2];
  const float* w2 = (const float*)d_in[3];
  const float* w3 = (const float*)d_in[4];
  float* out = (float*)d_out;

  char* ws = (char*)d_ws;
  int*    meta   = (int*)(ws + OFF_META);
  int*    tke    = (int*)(ws + OFF_TKE);
  float*  gateA  = (float*)(ws + OFF_GATE);
  int*    rowof  = (int*)(ws + OFF_ROWOF);
  int*    tokrow = (int*)(ws + OFF_TOKROW);
  __bf16* Xg     = (__bf16*)(ws + OFF_XG);
  __bf16* W1t    = (__bf16*)(ws + OFF_W1T);
  __bf16* W3t    = (__bf16*)(ws + OFF_W3T);
  __bf16* W2t    = (__bf16*)(ws + OFF_W2T);
  __bf16* Hb     = (__bf16*)(ws + OFF_H);
  __bf16* OP     = (__bf16*)(ws + OFF_OP);

  // memsets folded into kernels: meta <- transpose block(0,0,0);
  // tokrow=-1 <- router. (Two fewer serialized launches.)
  transpose_cvt_all<<<dim3(16, 12, 24), 256, 0, stream>>>(w1, w3, w2,
                                                          W1t, W3t, W2t, meta);
  router_kernel<<<RB, 256, 0, stream>>>(x, rw, meta, tke, gateA, tokrow);
  scan_kernel<<<1, 128, 0, stream>>>(meta, out + (size_t)NT * DD);
  scatter_kernel<<<NT/256, 256, 0, stream>>>(tke, meta, rowof, tokrow);
  gather_kernel<<<MAXROWS, 192, 0, stream>>>(x, tokrow, meta, Xg);

  gemm1_kernel<<<dim3(FF/64, MAXMT128), 256, 0, stream>>>(Xg, W1t, W3t, Hb, meta);
  gemm2_kernel<<<dim3(DD/128, MAXMT128), 256, 0, stream>>>(Hb, W2t, OP, meta);
  combine_kernel<<<NT, 192, 0, stream>>>(OP, rowof, gateA, out);
}